// Round 4
// baseline (53848.828 us; speedup 1.0000x reference)
//
#include <hip/hip_runtime.h>
#include <stdint.h>

typedef __attribute__((ext_vector_type(8))) short short8;
typedef __attribute__((ext_vector_type(4))) float float4v;

constexpr int T = 128;
constexpr int NB = 512;         // batch
constexpr int NGROUP = 4;       // batch groups (128 rows each)
constexpr int BPG = 64;         // blocks per group

__device__ __forceinline__ float bf2f(ushort u) {
  union { float f; uint32_t i; } v; v.i = ((uint32_t)u) << 16; return v.f;
}
__device__ __forceinline__ ushort f2bf(float f) {
  union { float f; uint32_t i; } v; v.f = f;
  uint32_t i = v.i;
  uint32_t r = i + 0x7FFFu + ((i >> 16) & 1u);
  return (ushort)(r >> 16);
}

// ---------------------------------------------------------------------------
// Pack f32 weights (optionally masked) into SPLIT bf16 MFMA B-fragment layout:
// hi at out[idx], lo at out[loOff+idx]; idx = ((kb*NT + nt)*64 + lane)*8 + jj
//   n = nt*16 + (lane&15), k = kb*32 + (lane>>4)*8 + jj ; zero-padded OOB.
// ---------------------------------------------------------------------------
__global__ __launch_bounds__(256) void pack_w(const float* __restrict__ W,
                                              const float* __restrict__ mask,
                                              ushort* __restrict__ out, int loOff,
                                              int NN, int IT, int NT, int KB) {
  int idx = blockIdx.x * 256 + threadIdx.x;
  int total = KB * NT * 512;
  if (idx >= total) return;
  int jj   = idx & 7;
  int lane = (idx >> 3) & 63;
  int nt   = (idx >> 9) % NT;
  int kb   = (idx >> 9) / NT;
  int n = nt * 16 + (lane & 15);
  int k = kb * 32 + (lane >> 4) * 8 + jj;
  float v = 0.f;
  if (n < NN && k < IT) {
    v = W[(size_t)n * IT + k];
    if (mask) v *= mask[(size_t)n * IT + k];
  }
  ushort hi = f2bf(v);
  out[idx] = hi;
  out[loOff + idx] = f2bf(v - bf2f(hi));
}

// ---------------------------------------------------------------------------
// One CfC cell tile job: 32 rows x (16*NTW) neurons, all 4 matrices (1/wave),
// split-bf16 3-term MFMA, epilogue h = tanh(ff1)*(1-s)+s*tanh(ff2).
// ---------------------------------------------------------------------------
template <int NTW>
__device__ __forceinline__ void cell_job(
    ushort* __restrict__ Ah, ushort* __restrict__ Al, float* __restrict__ Acc,
    const float* __restrict__ a0, int a0s, const float* __restrict__ a1, int a1s,
    int SEG1, int IT, int KB, int NT, int loOff,
    const ushort* const* __restrict__ wf4, const float* const* __restrict__ bias4,
    int NN, float* __restrict__ hout, float* __restrict__ out2,
    int b0, int ntp) {
  const int tid  = threadIdx.x;
  const int wave = tid >> 6, lane = tid & 63, quad = lane >> 4, l16 = lane & 15;
  const ushort* wfq = wf4[wave];
  const int nt0 = ntp * NTW;
  const int n0  = nt0 * 16;

  float4v acc[2][NTW];
#pragma unroll
  for (int i = 0; i < 2; i++)
#pragma unroll
    for (int w = 0; w < NTW; w++) acc[i][w] = float4v{0.f, 0.f, 0.f, 0.f};

  const int sm = tid >> 3;        // staging row 0..31
  const int sk = (tid & 7) * 4;   // staging col base
  const size_t ar0 = (size_t)(b0 + sm) * a0s;
  const size_t ar1 = (size_t)(b0 + sm) * a1s;

  for (int kb = 0; kb < KB; kb++) {
    const int k0 = kb * 32;
    // prefetch B fragments early (overlap with staging + syncs)
    short8 bh[NTW], bl[NTW];
#pragma unroll
    for (int w = 0; w < NTW; w++) {
      const size_t fo = ((size_t)(kb * NT + nt0 + w) * 64 + lane) * 8;
      bh[w] = *(const short8*)(wfq + fo);
      bl[w] = *(const short8*)(wfq + loOff + fo);
    }
    // A loads to regs
    float av[4];
#pragma unroll
    for (int e = 0; e < 4; e++) {
      int kg = k0 + sk + e;
      float v = 0.f;
      if (kg < SEG1)    v = a0[ar0 + kg];
      else if (kg < IT) v = a1[ar1 + (kg - SEG1)];
      av[e] = v;
    }
    __syncthreads();   // previous iteration's LDS reads complete
#pragma unroll
    for (int e = 0; e < 4; e++) {
      ushort hi = f2bf(av[e]);
      Ah[sm * 40 + sk + e] = hi;
      Al[sm * 40 + sk + e] = f2bf(av[e] - bf2f(hi));
    }
    __syncthreads();
#pragma unroll
    for (int mt = 0; mt < 2; mt++) {
      short8 ah = *(const short8*)&Ah[(mt * 16 + l16) * 40 + quad * 8];
      short8 al = *(const short8*)&Al[(mt * 16 + l16) * 40 + quad * 8];
#pragma unroll
      for (int w = 0; w < NTW; w++) {
        acc[mt][w] = __builtin_amdgcn_mfma_f32_16x16x32_bf16(ah, bh[w], acc[mt][w], 0, 0, 0);
        acc[mt][w] = __builtin_amdgcn_mfma_f32_16x16x32_bf16(al, bh[w], acc[mt][w], 0, 0, 0);
        acc[mt][w] = __builtin_amdgcn_mfma_f32_16x16x32_bf16(ah, bl[w], acc[mt][w], 0, 0, 0);
      }
    }
  }

  // spill accumulators to LDS for cross-wave (cross-matrix) combine
#pragma unroll
  for (int mt = 0; mt < 2; mt++)
#pragma unroll
    for (int w = 0; w < NTW; w++)
#pragma unroll
      for (int r = 0; r < 4; r++) {
        int row = mt * 16 + quad * 4 + r;
        int col = w * 16 + l16;
        Acc[(wave * 32 + row) * 49 + col] = acc[mt][w][r];
      }
  __syncthreads();

  // epilogue over 32 x (16*NTW) tile
  const int CW = 16 * NTW;
  for (int idx = tid; idx < 32 * CW; idx += 256) {
    int r = idx / CW, c = idx % CW;
    int j = n0 + c;
    if (j >= NN) continue;
    float v1 = Acc[(0 * 32 + r) * 49 + c] + bias4[0][j];
    float v2 = Acc[(1 * 32 + r) * 49 + c] + bias4[1][j];
    float va = Acc[(2 * 32 + r) * 49 + c] + bias4[2][j];
    float vb = Acc[(3 * 32 + r) * 49 + c] + bias4[3][j];
    float ff1 = tanhf(v1);
    float ff2 = tanhf(v2);
    float s = 1.f / (1.f + expf(-(va + vb)));
    float h = ff1 * (1.f - s) + s * ff2;
    size_t b = (size_t)(b0 + r);
    hout[b * 1024 + j] = h;
    if (out2) out2[b * 16384 + j] = h;   // pred[b][t][j]
  }
  // next job's first __syncthreads protects Ah/Al/Acc reuse
}

struct PParams {
  const float* x;
  float* h0; float* h1;
  const ushort* wf0[4]; const ushort* wf1[4]; const ushort* wf2[4];
  int loOff0, loOff1, loOff2;
  const float* bias0[4]; const float* bias1[4]; const float* bias2[4];
  float* pred;
  int* bar;
};

__device__ __forceinline__ void group_barrier(int* slot) {
  __threadfence();          // make this block's global writes device-visible
  __syncthreads();
  if (threadIdx.x == 0) {
    __hip_atomic_fetch_add(slot, 1, __ATOMIC_RELEASE, __HIP_MEMORY_SCOPE_AGENT);
    while (__hip_atomic_load(slot, __ATOMIC_ACQUIRE, __HIP_MEMORY_SCOPE_AGENT) < BPG) {
      __builtin_amdgcn_s_sleep(1);
    }
  }
  __syncthreads();
}

// ---------------------------------------------------------------------------
// Persistent kernel: 4 groups x 64 blocks; each group owns 128 batch rows and
// runs the full T=128 x 3-layer recurrence with group-local phase barriers.
// ---------------------------------------------------------------------------
__global__ __launch_bounds__(256) void cfc_persistent(PParams p) {
  __shared__ ushort Ah[32 * 40];
  __shared__ ushort Al[32 * 40];
  __shared__ float  Acc[4 * 32 * 49];
  const int blk = blockIdx.x;
  const int g = blk >> 6, lb = blk & 63;
  const int rowbase = g << 7;           // g * 128
  int* gbar = p.bar + g * (T * 3);

  for (int t = 0; t < T; t++) {
    float* hr = (t & 1) ? p.h1 : p.h0;
    float* hw = (t & 1) ? p.h0 : p.h1;
    // layer 0: xc = [x_t(512), h0_old(538)], 12 ntp(48-wide, NT padded to 36) x 4 mtc
    if (lb < 48) {
      int ntp = lb >> 2, mtc = lb & 3;
      cell_job<3>(Ah, Al, Acc, p.x + (size_t)t * 512, T * 512, hr, 1024,
                  512, 1050, 33, 36, p.loOff0, p.wf0, p.bias0, 538,
                  hw, nullptr, rowbase + mtc * 32, ntp);
    }
    group_barrier(gbar + t * 3);
    // layer 1: xc = [h0_new(538), h1_old(358)], 12 ntp(32-wide) x 4 mtc
    if (lb < 48) {
      int ntp = lb >> 2, mtc = lb & 3;
      cell_job<2>(Ah, Al, Acc, hw, 1024, hr + 538, 1024,
                  538, 896, 28, 24, p.loOff1, p.wf1, p.bias1, 358,
                  hw + 538, nullptr, rowbase + mtc * 32, ntp);
    }
    group_barrier(gbar + t * 3 + 1);
    // layer 2: xc = [h1_new(358), h2_old(128)], 4 ntp(32-wide) x 4 mtc
    if (lb < 16) {
      int ntp = lb >> 2, mtc = lb & 3;
      cell_job<2>(Ah, Al, Acc, hw + 538, 1024, hr + 896, 1024,
                  358, 486, 16, 8, p.loOff2, p.wf2, p.bias2, 128,
                  hw + 896, p.pred + (size_t)t * 128, rowbase + mtc * 32, ntp);
    }
    group_barrier(gbar + t * 3 + 2);
  }
}

// ---------------------------------------------------------------------------
// Final linear, IN PLACE on io (f32 d_out predictions region). Block owns its
// 64 rows: load->sync->overwrite. Split-bf16 precision.
// ---------------------------------------------------------------------------
__global__ __launch_bounds__(256)
void final_linear(float* __restrict__ io, const ushort* __restrict__ wfc_frag,
                  int loOff, const float* __restrict__ bfc) {
  __shared__ ushort Ah[64][136];
  __shared__ ushort Al[64][136];
  const int tid = threadIdx.x;
  const int wave = tid >> 6, lane = tid & 63, quad = lane >> 4, l16 = lane & 15;
  const size_t r0 = (size_t)blockIdx.x * 64;
  {
    const int row = tid >> 2;
    const int cb  = (tid & 3) * 32;
    const float* src = io + (r0 + row) * 128 + cb;
#pragma unroll
    for (int e = 0; e < 32; e++) {
      float v = src[e];
      ushort hi = f2bf(v);
      Ah[row][cb + e] = hi;
      Al[row][cb + e] = f2bf(v - bf2f(hi));
    }
  }
  __syncthreads();
  float4v acc[8];
#pragma unroll
  for (int i = 0; i < 8; i++) acc[i] = float4v{0.f, 0.f, 0.f, 0.f};
#pragma unroll
  for (int kb = 0; kb < 4; kb++) {
    short8 ah = *(const short8*)&Ah[wave * 16 + l16][kb * 32 + quad * 8];
    short8 al = *(const short8*)&Al[wave * 16 + l16][kb * 32 + quad * 8];
#pragma unroll
    for (int nt = 0; nt < 8; nt++) {
      const size_t fo = ((size_t)(kb * 8 + nt) * 64 + lane) * 8;
      short8 bh = *(const short8*)(wfc_frag + fo);
      short8 bl = *(const short8*)(wfc_frag + loOff + fo);
      acc[nt] = __builtin_amdgcn_mfma_f32_16x16x32_bf16(ah, bh, acc[nt], 0, 0, 0);
      acc[nt] = __builtin_amdgcn_mfma_f32_16x16x32_bf16(al, bh, acc[nt], 0, 0, 0);
      acc[nt] = __builtin_amdgcn_mfma_f32_16x16x32_bf16(ah, bl, acc[nt], 0, 0, 0);
    }
  }
  __syncthreads();
#pragma unroll
  for (int nt = 0; nt < 8; nt++) {
    int col = nt * 16 + l16;
    float bb = bfc[col];
#pragma unroll
    for (int r = 0; r < 4; r++) {
      int row = wave * 16 + quad * 4 + r;
      io[(r0 + row) * 128 + col] = acc[nt][r] + bb;
    }
  }
}

// ---------------------------------------------------------------------------
extern "C" void kernel_launch(void* const* d_in, const int* in_sizes, int n_in,
                              void* d_out, int out_size, void* d_ws, size_t ws_size,
                              hipStream_t stream) {
  const int maskIdx[3] = {2, 11, 20};
  const int wIdx[3]    = {3, 12, 21};
  const float* Wfc = (const float*)d_in[29];
  const float* bfc = (const float*)d_in[30];

  const int KBs[3] = {33, 28, 16};
  const int NTs[3] = {36, 24, 8};   // L0 padded 34->36 for 48-wide jobs
  const int NNs[3] = {538, 358, 128};
  const int ITs[3] = {1050, 896, 486};

  ushort* ws = (ushort*)d_ws;
  size_t off = 0;
  ushort* wf[3][4];
  int loOff[3];
  for (int l = 0; l < 3; l++) {
    loOff[l] = KBs[l] * NTs[l] * 512;
    for (int q = 0; q < 4; q++) {
      wf[l][q] = ws + off;
      off += (size_t)2 * loOff[l];
    }
  }
  int wfcLo = 4 * 8 * 512;
  ushort* wfc_f = ws + off; off += (size_t)2 * wfcLo;
  float* hb0 = (float*)(ws + off); off += (size_t)NB * 1024 * 2;
  float* hb1 = (float*)(ws + off); off += (size_t)NB * 1024 * 2;
  int* bar = (int*)(ws + off); off += NGROUP * T * 3 * 2;

  float* pred = (float*)d_out;
  float* hn   = (float*)d_out + (size_t)NB * T * 128;

  for (int l = 0; l < 3; l++) {
    int blocks = (loOff[l] + 255) / 256;
    for (int q = 0; q < 4; q++) {
      const float* m = (q < 2) ? (const float*)d_in[maskIdx[l]] : nullptr;
      pack_w<<<blocks, 256, 0, stream>>>((const float*)d_in[wIdx[l] + q], m, wf[l][q],
                                         loOff[l], NNs[l], ITs[l], NTs[l], KBs[l]);
    }
  }
  pack_w<<<(wfcLo + 255) / 256, 256, 0, stream>>>(Wfc, nullptr, wfc_f, wfcLo, 128, 128, 8, 4);

  hipMemsetAsync(bar, 0, NGROUP * T * 3 * sizeof(int), stream);
  hipMemcpyAsync(hb0, d_in[1], (size_t)NB * 1024 * sizeof(float),
                 hipMemcpyDeviceToDevice, stream);

  PParams p;
  p.x = (const float*)d_in[0];
  p.h0 = hb0; p.h1 = hb1;
  for (int q = 0; q < 4; q++) {
    p.wf0[q] = wf[0][q]; p.wf1[q] = wf[1][q]; p.wf2[q] = wf[2][q];
    p.bias0[q] = (const float*)d_in[7 + q];
    p.bias1[q] = (const float*)d_in[16 + q];
    p.bias2[q] = (const float*)d_in[25 + q];
  }
  p.loOff0 = loOff[0]; p.loOff1 = loOff[1]; p.loOff2 = loOff[2];
  p.pred = pred;
  p.bar = bar;

  cfc_persistent<<<NGROUP * BPG, 256, 0, stream>>>(p);

  final_linear<<<(NB * T) / 64, 256, 0, stream>>>(pred, wfc_f, wfcLo, bfc);
  hipMemcpyAsync(hn, hb0, (size_t)NB * 1024 * sizeof(float),
                 hipMemcpyDeviceToDevice, stream);
}

// Round 5
// 10693.274 us; speedup vs baseline: 5.0358x; 5.0358x over previous
//
#include <hip/hip_runtime.h>
#include <stdint.h>

typedef __attribute__((ext_vector_type(8))) short short8;
typedef __attribute__((ext_vector_type(4))) float float4v;

constexpr int T = 128;
constexpr int NB = 512;         // batch
constexpr int NGROUP = 4;       // batch groups (128 rows each)
constexpr int BPG = 64;         // blocks per group

__device__ __forceinline__ float bf2f(ushort u) {
  union { float f; uint32_t i; } v; v.i = ((uint32_t)u) << 16; return v.f;
}
__device__ __forceinline__ ushort f2bf(float f) {
  union { float f; uint32_t i; } v; v.f = f;
  uint32_t i = v.i;
  uint32_t r = i + 0x7FFFu + ((i >> 16) & 1u);
  return (ushort)(r >> 16);
}

// Coherent (L2-bypassing, sc0 sc1) accessors for cross-block h state.
// RELAXED+SYSTEM => plain global_load/store with sc0 sc1, NO buffer_inv/wbl2.
__device__ __forceinline__ float coh_load(const float* p) {
  return __hip_atomic_load(const_cast<float*>(p), __ATOMIC_RELAXED,
                           __HIP_MEMORY_SCOPE_SYSTEM);
}
__device__ __forceinline__ void coh_store(float* p, float v) {
  __hip_atomic_store(p, v, __ATOMIC_RELAXED, __HIP_MEMORY_SCOPE_SYSTEM);
}

// ---------------------------------------------------------------------------
// Pack f32 weights (optionally masked) into SPLIT bf16 MFMA B-fragment layout.
// ---------------------------------------------------------------------------
__global__ __launch_bounds__(256) void pack_w(const float* __restrict__ W,
                                              const float* __restrict__ mask,
                                              ushort* __restrict__ out, int loOff,
                                              int NN, int IT, int NT, int KB) {
  int idx = blockIdx.x * 256 + threadIdx.x;
  int total = KB * NT * 512;
  if (idx >= total) return;
  int jj   = idx & 7;
  int lane = (idx >> 3) & 63;
  int nt   = (idx >> 9) % NT;
  int kb   = (idx >> 9) / NT;
  int n = nt * 16 + (lane & 15);
  int k = kb * 32 + (lane >> 4) * 8 + jj;
  float v = 0.f;
  if (n < NN && k < IT) {
    v = W[(size_t)n * IT + k];
    if (mask) v *= mask[(size_t)n * IT + k];
  }
  ushort hi = f2bf(v);
  out[idx] = hi;
  out[loOff + idx] = f2bf(v - bf2f(hi));
}

// ---------------------------------------------------------------------------
// One CfC cell tile job: 32 rows x (16*NTW) neurons, all 4 matrices (1/wave),
// split-bf16 3-term MFMA with B double-buffer + A prefetch.
// C0/C1: whether a0/a1 need coherent (bypass) loads.
// ---------------------------------------------------------------------------
template <int NTW, bool C0, bool C1>
__device__ __forceinline__ void cell_job(
    ushort* __restrict__ Ah, ushort* __restrict__ Al, float* __restrict__ Acc,
    const float* __restrict__ a0, int a0s, const float* __restrict__ a1, int a1s,
    int SEG1, int IT, int KB, int NT, int loOff,
    const ushort* const* __restrict__ wf4, const float* const* __restrict__ bias4,
    int NN, float* __restrict__ hout, float* __restrict__ out2,
    int b0, int ntp) {
  const int tid  = threadIdx.x;
  const int wave = tid >> 6, lane = tid & 63, quad = lane >> 4, l16 = lane & 15;
  const ushort* wfq = wf4[wave];
  const int nt0 = ntp * NTW;
  const int n0  = nt0 * 16;

  float4v acc[2][NTW];
#pragma unroll
  for (int i = 0; i < 2; i++)
#pragma unroll
    for (int w = 0; w < NTW; w++) acc[i][w] = float4v{0.f, 0.f, 0.f, 0.f};

  const int sm = tid >> 3;        // staging row 0..31
  const int sk = (tid & 7) * 4;   // staging col base
  const size_t ar0 = (size_t)(b0 + sm) * a0s;
  const size_t ar1 = (size_t)(b0 + sm) * a1s;

  short8 cbh[NTW], cbl[NTW];
  float av[4];

  auto loadB = [&](int kb, short8* bh, short8* bl) {
#pragma unroll
    for (int w = 0; w < NTW; w++) {
      const size_t fo = ((size_t)(kb * NT + nt0 + w) * 64 + lane) * 8;
      bh[w] = *(const short8*)(wfq + fo);
      bl[w] = *(const short8*)(wfq + loOff + fo);
    }
  };
  auto loadA = [&](int kb) {
    const int k0 = kb * 32;
#pragma unroll
    for (int e = 0; e < 4; e++) {
      int kg = k0 + sk + e;
      float v = 0.f;
      if (kg < SEG1)    v = C0 ? coh_load(a0 + ar0 + kg) : a0[ar0 + kg];
      else if (kg < IT) v = C1 ? coh_load(a1 + ar1 + (kg - SEG1)) : a1[ar1 + (kg - SEG1)];
      av[e] = v;
    }
  };

  loadB(0, cbh, cbl);
  loadA(0);

  for (int kb = 0; kb < KB; kb++) {
    __syncthreads();   // previous iteration's LDS reads complete
#pragma unroll
    for (int e = 0; e < 4; e++) {
      ushort hi = f2bf(av[e]);
      Ah[sm * 40 + sk + e] = hi;
      Al[sm * 40 + sk + e] = f2bf(av[e] - bf2f(hi));
    }
    __syncthreads();

    short8 nbh[NTW], nbl[NTW];
    const bool more = (kb + 1 < KB);
    if (more) {
      loadA(kb + 1);
      loadB(kb + 1, nbh, nbl);
    }

#pragma unroll
    for (int mt = 0; mt < 2; mt++) {
      short8 ah = *(const short8*)&Ah[(mt * 16 + l16) * 40 + quad * 8];
      short8 al = *(const short8*)&Al[(mt * 16 + l16) * 40 + quad * 8];
#pragma unroll
      for (int w = 0; w < NTW; w++) {
        acc[mt][w] = __builtin_amdgcn_mfma_f32_16x16x32_bf16(ah, cbh[w], acc[mt][w], 0, 0, 0);
        acc[mt][w] = __builtin_amdgcn_mfma_f32_16x16x32_bf16(al, cbh[w], acc[mt][w], 0, 0, 0);
        acc[mt][w] = __builtin_amdgcn_mfma_f32_16x16x32_bf16(ah, cbl[w], acc[mt][w], 0, 0, 0);
      }
    }
    if (more) {
#pragma unroll
      for (int w = 0; w < NTW; w++) { cbh[w] = nbh[w]; cbl[w] = nbl[w]; }
    }
  }

  // spill accumulators to LDS for cross-wave (cross-matrix) combine
#pragma unroll
  for (int mt = 0; mt < 2; mt++)
#pragma unroll
    for (int w = 0; w < NTW; w++)
#pragma unroll
      for (int r = 0; r < 4; r++) {
        int row = mt * 16 + quad * 4 + r;
        int col = w * 16 + l16;
        Acc[(wave * 32 + row) * 50 + col] = acc[mt][w][r];
      }
  __syncthreads();

  // epilogue over 32 x (16*NTW) tile
  const int CW = 16 * NTW;
  for (int idx = tid; idx < 32 * CW; idx += 256) {
    int r = idx / CW, c = idx % CW;
    int j = n0 + c;
    if (j >= NN) continue;
    float v1 = Acc[(0 * 32 + r) * 50 + c] + bias4[0][j];
    float v2 = Acc[(1 * 32 + r) * 50 + c] + bias4[1][j];
    float va = Acc[(2 * 32 + r) * 50 + c] + bias4[2][j];
    float vb = Acc[(3 * 32 + r) * 50 + c] + bias4[3][j];
    float ff1 = tanhf(v1);
    float ff2 = tanhf(v2);
    float s = 1.f / (1.f + expf(-(va + vb)));
    float h = ff1 * (1.f - s) + s * ff2;
    size_t b = (size_t)(b0 + r);
    coh_store(hout + b * 1024 + j, h);        // cross-block state: bypass L2
    if (out2) out2[b * 16384 + j] = h;        // pred: consumed next dispatch
  }
}

struct PParams {
  const float* x;
  float* h0; float* h1;
  const ushort* wf0[4]; const ushort* wf1[4]; const ushort* wf2[4];
  int loOff0, loOff1, loOff2;
  const float* bias0[4]; const float* bias1[4]; const float* bias2[4];
  float* pred;
  int* bar;
};

// Group barrier with NO cache-maintenance ops: each thread drains its own
// coherent stores (vmcnt ack = reached coherence point), then one RELAXED
// system-scope add + spin. Monotonic slots (memset once) -> no ABA, no reset.
__device__ __forceinline__ void group_barrier(int* slot) {
  asm volatile("s_waitcnt vmcnt(0)" ::: "memory");
  __syncthreads();
  if (threadIdx.x == 0) {
    __hip_atomic_fetch_add(slot, 1, __ATOMIC_RELAXED, __HIP_MEMORY_SCOPE_SYSTEM);
    while (__hip_atomic_load(slot, __ATOMIC_RELAXED, __HIP_MEMORY_SCOPE_SYSTEM) < BPG)
      __builtin_amdgcn_s_sleep(1);
  }
  __syncthreads();
}

// ---------------------------------------------------------------------------
// Persistent kernel: 4 groups x 64 blocks; each group owns 128 batch rows.
// 256 blocks <= 256 CUs at 1 block/CU min occupancy -> co-residency safe.
// ---------------------------------------------------------------------------
__global__ __launch_bounds__(256) void cfc_persistent(PParams p) {
  __shared__ ushort Ah[32 * 40];
  __shared__ ushort Al[32 * 40];
  __shared__ float  Acc[4 * 32 * 50];
  const int blk = blockIdx.x;
  const int g = blk >> 6, lb = blk & 63;
  const int rowbase = g << 7;
  int* gbar = p.bar + g * (T * 3);

  for (int t = 0; t < T; t++) {
    float* hr = (t & 1) ? p.h1 : p.h0;
    float* hw = (t & 1) ? p.h0 : p.h1;
    // layer 0: xc = [x_t(512) cached, h0_old(538) coherent]
    if (lb < 48) {
      int ntp = lb >> 2, mtc = lb & 3;
      cell_job<3, false, true>(Ah, Al, Acc, p.x + (size_t)t * 512, T * 512, hr, 1024,
                               512, 1050, 33, 36, p.loOff0, p.wf0, p.bias0, 538,
                               hw, nullptr, rowbase + mtc * 32, ntp);
    }
    group_barrier(gbar + t * 3);
    // layer 1: xc = [h0_new(538), h1_old(358)]
    if (lb < 48) {
      int ntp = lb >> 2, mtc = lb & 3;
      cell_job<2, true, true>(Ah, Al, Acc, hw, 1024, hr + 538, 1024,
                              538, 896, 28, 24, p.loOff1, p.wf1, p.bias1, 358,
                              hw + 538, nullptr, rowbase + mtc * 32, ntp);
    }
    group_barrier(gbar + t * 3 + 1);
    // layer 2: xc = [h1_new(358), h2_old(128)]; writes pred[:, t, :]
    if (lb < 16) {
      int ntp = lb >> 2, mtc = lb & 3;
      cell_job<2, true, true>(Ah, Al, Acc, hw + 538, 1024, hr + 896, 1024,
                              358, 486, 16, 8, p.loOff2, p.wf2, p.bias2, 128,
                              hw + 896, p.pred + (size_t)t * 128, rowbase + mtc * 32, ntp);
    }
    group_barrier(gbar + t * 3 + 2);
  }
}

// ---------------------------------------------------------------------------
// Final linear, IN PLACE on io (f32 d_out predictions region).
// ---------------------------------------------------------------------------
__global__ __launch_bounds__(256)
void final_linear(float* __restrict__ io, const ushort* __restrict__ wfc_frag,
                  int loOff, const float* __restrict__ bfc) {
  __shared__ ushort Ah[64][136];
  __shared__ ushort Al[64][136];
  const int tid = threadIdx.x;
  const int wave = tid >> 6, lane = tid & 63, quad = lane >> 4, l16 = lane & 15;
  const size_t r0 = (size_t)blockIdx.x * 64;
  {
    const int row = tid >> 2;
    const int cb  = (tid & 3) * 32;
    const float* src = io + (r0 + row) * 128 + cb;
#pragma unroll
    for (int e = 0; e < 32; e++) {
      float v = src[e];
      ushort hi = f2bf(v);
      Ah[row][cb + e] = hi;
      Al[row][cb + e] = f2bf(v - bf2f(hi));
    }
  }
  __syncthreads();
  float4v acc[8];
#pragma unroll
  for (int i = 0; i < 8; i++) acc[i] = float4v{0.f, 0.f, 0.f, 0.f};
#pragma unroll
  for (int kb = 0; kb < 4; kb++) {
    short8 ah = *(const short8*)&Ah[wave * 16 + l16][kb * 32 + quad * 8];
    short8 al = *(const short8*)&Al[wave * 16 + l16][kb * 32 + quad * 8];
#pragma unroll
    for (int nt = 0; nt < 8; nt++) {
      const size_t fo = ((size_t)(kb * 8 + nt) * 64 + lane) * 8;
      short8 bh = *(const short8*)(wfc_frag + fo);
      short8 bl = *(const short8*)(wfc_frag + loOff + fo);
      acc[nt] = __builtin_amdgcn_mfma_f32_16x16x32_bf16(ah, bh, acc[nt], 0, 0, 0);
      acc[nt] = __builtin_amdgcn_mfma_f32_16x16x32_bf16(al, bh, acc[nt], 0, 0, 0);
      acc[nt] = __builtin_amdgcn_mfma_f32_16x16x32_bf16(ah, bl, acc[nt], 0, 0, 0);
    }
  }
  __syncthreads();
#pragma unroll
  for (int nt = 0; nt < 8; nt++) {
    int col = nt * 16 + l16;
    float bb = bfc[col];
#pragma unroll
    for (int r = 0; r < 4; r++) {
      int row = wave * 16 + quad * 4 + r;
      io[(r0 + row) * 128 + col] = acc[nt][r] + bb;
    }
  }
}

// ---------------------------------------------------------------------------
extern "C" void kernel_launch(void* const* d_in, const int* in_sizes, int n_in,
                              void* d_out, int out_size, void* d_ws, size_t ws_size,
                              hipStream_t stream) {
  const int maskIdx[3] = {2, 11, 20};
  const int wIdx[3]    = {3, 12, 21};
  const float* Wfc = (const float*)d_in[29];
  const float* bfc = (const float*)d_in[30];

  const int KBs[3] = {33, 28, 16};
  const int NTs[3] = {36, 24, 8};   // L0 padded 34->36 for 48-wide jobs
  const int NNs[3] = {538, 358, 128};
  const int ITs[3] = {1050, 896, 486};

  ushort* ws = (ushort*)d_ws;
  size_t off = 0;
  ushort* wf[3][4];
  int loOff[3];
  for (int l = 0; l < 3; l++) {
    loOff[l] = KBs[l] * NTs[l] * 512;
    for (int q = 0; q < 4; q++) {
      wf[l][q] = ws + off;
      off += (size_t)2 * loOff[l];
    }
  }
  int wfcLo = 4 * 8 * 512;
  ushort* wfc_f = ws + off; off += (size_t)2 * wfcLo;
  float* hb0 = (float*)(ws + off); off += (size_t)NB * 1024 * 2;
  float* hb1 = (float*)(ws + off); off += (size_t)NB * 1024 * 2;
  int* bar = (int*)(ws + off); off += NGROUP * T * 3 * 2;

  float* pred = (float*)d_out;
  float* hn   = (float*)d_out + (size_t)NB * T * 128;

  for (int l = 0; l < 3; l++) {
    int blocks = (loOff[l] + 255) / 256;
    for (int q = 0; q < 4; q++) {
      const float* m = (q < 2) ? (const float*)d_in[maskIdx[l]] : nullptr;
      pack_w<<<blocks, 256, 0, stream>>>((const float*)d_in[wIdx[l] + q], m, wf[l][q],
                                         loOff[l], NNs[l], ITs[l], NTs[l], KBs[l]);
    }
  }
  pack_w<<<(wfcLo + 255) / 256, 256, 0, stream>>>(Wfc, nullptr, wfc_f, wfcLo, 128, 128, 8, 4);

  hipMemsetAsync(bar, 0, NGROUP * T * 3 * sizeof(int), stream);
  hipMemcpyAsync(hb0, d_in[1], (size_t)NB * 1024 * sizeof(float),
                 hipMemcpyDeviceToDevice, stream);

  PParams p;
  p.x = (const float*)d_in[0];
  p.h0 = hb0; p.h1 = hb1;
  for (int q = 0; q < 4; q++) {
    p.wf0[q] = wf[0][q]; p.wf1[q] = wf[1][q]; p.wf2[q] = wf[2][q];
    p.bias0[q] = (const float*)d_in[7 + q];
    p.bias1[q] = (const float*)d_in[16 + q];
    p.bias2[q] = (const float*)d_in[25 + q];
  }
  p.loOff0 = loOff[0]; p.loOff1 = loOff[1]; p.loOff2 = loOff[2];
  p.pred = pred;
  p.bar = bar;

  cfc_persistent<<<NGROUP * BPG, 256, 0, stream>>>(p);

  final_linear<<<(NB * T) / 64, 256, 0, stream>>>(pred, wfc_f, wfcLo, bfc);
  hipMemcpyAsync(hn, hb0, (size_t)NB * 1024 * sizeof(float),
                 hipMemcpyDeviceToDevice, stream);
}